// Round 4
// baseline (441.129 us; speedup 1.0000x reference)
//
#include <hip/hip_runtime.h>
#include <hip/hip_bf16.h>

typedef __attribute__((ext_vector_type(8))) short bf16x8;
typedef __attribute__((ext_vector_type(4))) float f32x4;
typedef __attribute__((ext_vector_type(8))) unsigned short u16x8;
typedef __attribute__((ext_vector_type(4))) unsigned short u16x4;

#define BN_EPS 1e-5f

__device__ __forceinline__ unsigned short f2bf(float f) {
  unsigned int u = __float_as_uint(f);
  unsigned int r = u + 0x7FFFu + ((u >> 16) & 1u);
  return (unsigned short)(r >> 16);
}
__device__ __forceinline__ float bf2f(unsigned short u) {
  union { float f; unsigned int i; } v; v.i = ((unsigned int)u) << 16; return v.f;
}

// async global->LDS, 16B per lane. LDS dest = uniform base + lane*16.
__device__ __forceinline__ void async_ld16(const unsigned short* g, unsigned short* l) {
  __builtin_amdgcn_global_load_lds(
      (const __attribute__((address_space(1))) void*)g,
      (__attribute__((address_space(3))) void*)l, 16, 0, 0);
}

// ---------------------------------------------------------------------------
// K0: fold BN params -> bias1[256], W2f[9*256] (scale folded), bias2[9]
__global__ __launch_bounds__(256) void params_kernel(
    const float* __restrict__ g1, const float* __restrict__ b1,
    const float* __restrict__ m1, const float* __restrict__ v1,
    const float* __restrict__ W2, const float* __restrict__ g2,
    const float* __restrict__ b2, const float* __restrict__ m2,
    const float* __restrict__ v2,
    float* __restrict__ bias1, float* __restrict__ W2f, float* __restrict__ bias2)
{
  int t = threadIdx.x;
  {
    float s = g1[t] * rsqrtf(v1[t] + BN_EPS);
    bias1[t] = b1[t] - m1[t] * s;
  }
  for (int i = t; i < 2304; i += 256) {
    int j = i >> 8;
    float s2 = g2[j] * rsqrtf(v2[j] + BN_EPS);
    W2f[i] = W2[i] * s2;
  }
  if (t < 9) {
    float s2 = g2[t] * rsqrtf(v2[t] + BN_EPS);
    bias2[t] = b2[t] - m2[t] * s2;
  }
}

// ---------------------------------------------------------------------------
// K1: fold scale1 into W1, quantize bf16, transpose to Bt[o][tap*256 + i]
__global__ __launch_bounds__(256) void fold_w1_kernel(
    const float* __restrict__ W1, const float* __restrict__ g1,
    const float* __restrict__ v1, unsigned short* __restrict__ Bt)
{
  int idx = blockIdx.x * 256 + threadIdx.x;   // 0 .. 589823
  int o = idx / 2304;
  int k = idx - o * 2304;
  int tap = k >> 8;
  int i = k & 255;
  float s = g1[o] * rsqrtf(v1[o] + BN_EPS);
  Bt[idx] = f2bf(W1[o * 2304 + i * 9 + tap] * s);
}

// ---------------------------------------------------------------------------
// K1b: zero only the pad border of yTp (replaces 35 MB memset)
__global__ __launch_bounds__(256) void border_zero_kernel(unsigned short* __restrict__ yTp)
{
  int n = blockIdx.x, t = threadIdx.x;
  size_t base = (size_t)n * 66 * 66 * 256;
  u16x8 z = (u16x8){0, 0, 0, 0, 0, 0, 0, 0};
  // rows hh=0 and hh=65 (full 66*256 each)
  for (int i = t; i < 2112; i += 256) {
    *(u16x8*)(yTp + base + (size_t)i * 8) = z;
    *(u16x8*)(yTp + base + (size_t)65 * 66 * 256 + (size_t)i * 8) = z;
  }
  // cols ww=0 and ww=65 for hh=1..64
  for (int i = t; i < 2048; i += 256) {
    int hh = 1 + (i >> 5);
    int off = (i & 31) * 8;
    *(u16x8*)(yTp + base + ((size_t)hh * 66 + 0) * 256 + off) = z;
    *(u16x8*)(yTp + base + ((size_t)hh * 66 + 65) * 256 + off) = z;
  }
}

// ---------------------------------------------------------------------------
// K2: y (fp32 NCHW) -> zero-padded bf16 NHWC yTp[n][hh][ww][c], hh,ww in [0,66)
__global__ __launch_bounds__(256) void transpose_pad_kernel(
    const float* __restrict__ y, unsigned short* __restrict__ yTp)
{
  __shared__ unsigned short T[64][68];
  int t = threadIdx.x;
  int nb = blockIdx.x; int n = nb >> 6, h = nb & 63;
  int w4 = (t & 15) * 4;
  int cl = t >> 4;
  int cw = t & 63;
  int wi = t >> 6;
  for (int cb = 0; cb < 4; ++cb) {
    __syncthreads();
    #pragma unroll
    for (int r = 0; r < 4; ++r) {
      int c = cb * 64 + cl + r * 16;
      const float* src = y + ((((size_t)n * 256 + c) * 64 + h) << 6) + w4;
      float4 v = *(const float4*)src;
      u16x4 pv = { f2bf(v.x), f2bf(v.y), f2bf(v.z), f2bf(v.w) };
      *(u16x4*)&T[cl + r * 16][w4] = pv;
    }
    __syncthreads();
    size_t obase = ((((size_t)n * 66 + (h + 1)) * 66) + 1) * 256 + cb * 64 + cw;
    #pragma unroll
    for (int r = 0; r < 16; ++r) {
      int w = wi + r * 4;
      yTp[obase + (size_t)w * 256] = T[cw][w];
    }
  }
}

// ---------------------------------------------------------------------------
// K3: conv3x3 implicit GEMM, m97-style. Block = 128 pixels x 128 c_out,
// BK=32, global_load_lds staging, quad-plane LDS layout [q][row][8shorts].
// 4 waves in 2x2, each 64x64 via 4x4 of mfma_f32_16x16x32_bf16.
__global__ __launch_bounds__(256, 3) void conv3x3_mfma_kernel(
    const unsigned short* __restrict__ yTp, const unsigned short* __restrict__ Bt,
    const float* __restrict__ bias1, const float* __restrict__ a1p,
    unsigned short* __restrict__ hT)
{
  __shared__ unsigned short Als[4][128][8];   // 8 KB
  __shared__ unsigned short Bls[4][128][8];   // 8 KB
  int tid = threadIdx.x;
  int w = tid >> 6, l = tid & 63;
  int lr = l & 15, quad = l >> 4;
  int wm = w >> 1, wn = w & 1;
  int bid = blockIdx.x;
  int bn = bid & 1, bm = bid >> 1;            // bm 0..511
  int n = bm >> 5, hb = (bm & 31) * 2;        // two h rows per block

  f32x4 acc[4][4];
  #pragma unroll
  for (int im = 0; im < 4; ++im)
    #pragma unroll
    for (int in_ = 0; in_ < 4; ++in_)
      acc[im][in_] = (f32x4){0.f, 0.f, 0.f, 0.f};

  const size_t nbase = (size_t)n * 66 * 66;
  // per-lane invariant bases
  const unsigned short* aBase0 = yTp + ((nbase + (size_t)(hb + 0) * 66 + l) << 8);
  const unsigned short* aBase1 = yTp + ((nbase + (size_t)(hb + 1) * 66 + l) << 8);
  const unsigned short* bBase0 = Bt + (size_t)(bn * 128 + l) * 2304;
  const unsigned short* bBase1 = Bt + (size_t)(bn * 128 + 64 + l) * 2304;
  int q0 = (w & 1) * 2;   // waves 0,2 -> planes 0,1 ; waves 1,3 -> planes 2,3

  for (int it = 0; it < 72; ++it) {
    int tap = it >> 3;
    int ci0 = (it & 7) << 5;
    int ti = tap / 3;
    int tj = tap - 3 * ti;
    __syncthreads();
    if (w < 2) {
      size_t uoff = ((size_t)(ti * 66 + tj) << 8) + ci0 + q0 * 8;
      async_ld16(aBase0 + uoff,     &Als[q0][0][0]);
      async_ld16(aBase1 + uoff,     &Als[q0][64][0]);
      async_ld16(aBase0 + uoff + 8, &Als[q0 + 1][0][0]);
      async_ld16(aBase1 + uoff + 8, &Als[q0 + 1][64][0]);
    } else {
      size_t uoff = (size_t)(tap << 8) + ci0 + q0 * 8;
      async_ld16(bBase0 + uoff,     &Bls[q0][0][0]);
      async_ld16(bBase1 + uoff,     &Bls[q0][64][0]);
      async_ld16(bBase0 + uoff + 8, &Bls[q0 + 1][0][0]);
      async_ld16(bBase1 + uoff + 8, &Bls[q0 + 1][64][0]);
    }
    __syncthreads();
    bf16x8 af[4], bfr[4];
    #pragma unroll
    for (int im = 0; im < 4; ++im)
      af[im] = *(const bf16x8*)&Als[quad][wm * 64 + im * 16 + lr][0];
    #pragma unroll
    for (int in_ = 0; in_ < 4; ++in_)
      bfr[in_] = *(const bf16x8*)&Bls[quad][wn * 64 + in_ * 16 + lr][0];
    #pragma unroll
    for (int im = 0; im < 4; ++im)
      #pragma unroll
      for (int in_ = 0; in_ < 4; ++in_)
        acc[im][in_] = __builtin_amdgcn_mfma_f32_16x16x32_bf16(
            af[im], bfr[in_], acc[im][in_], 0, 0, 0);
  }

  float a1 = a1p[0];
  size_t pix0 = (size_t)bm * 128 + wm * 64;
  #pragma unroll
  for (int in_ = 0; in_ < 4; ++in_) {
    int c = bn * 128 + wn * 64 + in_ * 16 + lr;
    float bs = bias1[c];
    #pragma unroll
    for (int im = 0; im < 4; ++im) {
      size_t m0 = pix0 + im * 16 + quad * 4;
      #pragma unroll
      for (int r = 0; r < 4; ++r) {
        float v = acc[im][in_][r] + bs;
        v = (v >= 0.f) ? v : a1 * v;
        hT[(m0 + r) * 256 + c] = f2bf(v);
      }
    }
  }
}

// ---------------------------------------------------------------------------
// K4: 1x1 conv C->9 + BN + PReLU. 4 lanes per pixel, shfl reduce.
__global__ __launch_bounds__(256) void conv1x1_kernel(
    const unsigned short* __restrict__ hT, const float* __restrict__ W2f,
    const float* __restrict__ bias2, const float* __restrict__ a2p,
    float* __restrict__ kernP)
{
  __shared__ float w2s[2304];
  int t = threadIdx.x;
  for (int i = t; i < 2304; i += 256) w2s[i] = W2f[i];
  __syncthreads();
  int seg = t & 3;
  int pr = t >> 2;
  int p = blockIdx.x * 64 + pr;
  const unsigned short* hp = hT + (size_t)p * 256;
  float acc[9];
  #pragma unroll
  for (int j = 0; j < 9; ++j) acc[j] = 0.f;
  for (int c0 = seg * 8; c0 < 256; c0 += 32) {
    u16x8 hv = *(const u16x8*)(hp + c0);
    float hf[8];
    #pragma unroll
    for (int i = 0; i < 8; ++i) hf[i] = bf2f(hv[i]);
    #pragma unroll
    for (int j = 0; j < 9; ++j)
      #pragma unroll
      for (int i = 0; i < 8; ++i)
        acc[j] = fmaf(hf[i], w2s[j * 256 + c0 + i], acc[j]);
  }
  #pragma unroll
  for (int j = 0; j < 9; ++j) {
    acc[j] += __shfl_xor(acc[j], 1);
    acc[j] += __shfl_xor(acc[j], 2);
  }
  if (seg == 0) {
    float a2 = a2p[0];
    #pragma unroll
    for (int j = 0; j < 9; ++j) {
      float v = acc[j] + bias2[j];
      v = (v >= 0.f) ? v : a2 * v;
      kernP[j * 65536 + p] = v;
    }
  }
}

// ---------------------------------------------------------------------------
// K5: scrambled unfold-reshape apply (reference's row-major reshape).
__global__ __launch_bounds__(256) void apply_dyn_kernel(
    const float* __restrict__ x, const float* __restrict__ kernP,
    float* __restrict__ out)
{
  __shared__ float xs[64 * 65];
  __shared__ float ks[9][16];
  int t = threadIdx.x;
  int b = blockIdx.x;             // ((n*64 + h')*4 + g)
  int g = b & 3;
  int nh = b >> 2;
  int n = nh >> 6, hp = nh & 63;
  int c = 4 * hp + g;

  const float* xplane = x + (((size_t)n * 256 + c) << 12);
  for (int i = t; i < 1024; i += 256) {
    float4 v = *(const float4*)(xplane + i * 4);
    int row = i >> 4;
    int col = (i * 4) & 63;
    float* d = &xs[row * 65 + col];
    d[0] = v.x; d[1] = v.y; d[2] = v.z; d[3] = v.w;
  }
  int pbase = n * 4096 + hp * 64 + g * 16;
  for (int i = t; i < 144; i += 256)
    ks[i / 16][i & 15] = kernP[(i / 16) * 65536 + pbase + (i & 15)];
  __syncthreads();

  int s = t & 15;
  int crow = t >> 4;
  float ksr[9];
  #pragma unroll
  for (int k2 = 0; k2 < 9; ++k2) ksr[k2] = ks[k2][s];

  int r0base = s * 2304 + crow * 9;
  #pragma unroll 4
  for (int jj = 0; jj < 16; ++jj) {
    int cp = crow + 16 * jj;
    int r0 = r0base + 144 * jj;
    float acc = 0.f;
    #pragma unroll
    for (int k2 = 0; k2 < 9; ++k2) {
      int r = r0 + k2;
      int k = r >> 12;
      int rem = r & 4095;
      int h = rem >> 6;
      int w = rem & 63;
      int ti = k / 3;
      int tj = k - 3 * ti;
      int hh = h + ti - 1;
      int ww = w + tj - 1;
      float xv = 0.f;
      if ((unsigned)hh < 64u && (unsigned)ww < 64u) xv = xs[hh * 65 + ww];
      acc = fmaf(xv, ksr[k2], acc);
    }
    out[(((size_t)n * 256 + cp) << 12) + (hp << 6) + g * 16 + s] = acc;
  }
}

// ---------------------------------------------------------------------------
extern "C" void kernel_launch(void* const* d_in, const int* in_sizes, int n_in,
                              void* d_out, int out_size, void* d_ws, size_t ws_size,
                              hipStream_t stream) {
  const float* x  = (const float*)d_in[0];
  const float* y  = (const float*)d_in[1];
  const float* W1 = (const float*)d_in[2];
  const float* g1 = (const float*)d_in[3];
  const float* b1 = (const float*)d_in[4];
  const float* m1 = (const float*)d_in[5];
  const float* v1 = (const float*)d_in[6];
  const float* a1 = (const float*)d_in[7];
  const float* W2 = (const float*)d_in[8];
  const float* g2 = (const float*)d_in[9];
  const float* b2 = (const float*)d_in[10];
  const float* m2 = (const float*)d_in[11];
  const float* v2 = (const float*)d_in[12];
  const float* a2 = (const float*)d_in[13];
  float* out = (float*)d_out;

  char* ws = (char*)d_ws;
  size_t off = 0;
  const size_t yTp_bytes = (size_t)16 * 66 * 66 * 256 * 2;
  unsigned short* yTp = (unsigned short*)(ws + off); off += yTp_bytes;
  unsigned short* Bt  = (unsigned short*)(ws + off); off += (size_t)589824 * 2;
  unsigned short* hT  = (unsigned short*)(ws + off); off += (size_t)16777216 * 2;
  float* kernP = (float*)(ws + off); off += (size_t)589824 * 4;
  float* bias1 = (float*)(ws + off); off += 1024;
  float* W2f   = (float*)(ws + off); off += 9216;
  float* bias2 = (float*)(ws + off); off += 64;

  params_kernel<<<1, 256, 0, stream>>>(g1, b1, m1, v1, W2, g2, b2, m2, v2,
                                       bias1, W2f, bias2);
  fold_w1_kernel<<<2304, 256, 0, stream>>>(W1, g1, v1, Bt);
  border_zero_kernel<<<16, 256, 0, stream>>>(yTp);
  transpose_pad_kernel<<<1024, 256, 0, stream>>>(y, yTp);
  conv3x3_mfma_kernel<<<1024, 256, 0, stream>>>(yTp, Bt, bias1, a1, hT);
  conv1x1_kernel<<<1024, 256, 0, stream>>>(hT, W2f, bias2, a2, kernP);
  apply_dyn_kernel<<<4096, 256, 0, stream>>>(x, kernP, out);
}

// Round 5
// 370.969 us; speedup vs baseline: 1.1891x; 1.1891x over previous
//
#include <hip/hip_runtime.h>
#include <hip/hip_bf16.h>

typedef __attribute__((ext_vector_type(8))) short bf16x8;
typedef __attribute__((ext_vector_type(4))) float f32x4;
typedef __attribute__((ext_vector_type(8))) unsigned short u16x8;
typedef __attribute__((ext_vector_type(4))) unsigned short u16x4;

#define BN_EPS 1e-5f

__device__ __forceinline__ unsigned short f2bf(float f) {
  unsigned int u = __float_as_uint(f);
  unsigned int r = u + 0x7FFFu + ((u >> 16) & 1u);
  return (unsigned short)(r >> 16);
}
__device__ __forceinline__ float bf2f(unsigned short u) {
  union { float f; unsigned int i; } v; v.i = ((unsigned int)u) << 16; return v.f;
}

// async global->LDS, 16B per lane. LDS dest = wave-uniform base + lane*16.
__device__ __forceinline__ void async_ld16(const unsigned short* g, unsigned short* l) {
  __builtin_amdgcn_global_load_lds(
      (const __attribute__((address_space(1))) void*)g,
      (__attribute__((address_space(3))) void*)l, 16, 0, 0);
}

// ---------------------------------------------------------------------------
// K0: fold BN params -> bias1[256], W2f[9*256] (scale folded), bias2[9]
__global__ __launch_bounds__(256) void params_kernel(
    const float* __restrict__ g1, const float* __restrict__ b1,
    const float* __restrict__ m1, const float* __restrict__ v1,
    const float* __restrict__ W2, const float* __restrict__ g2,
    const float* __restrict__ b2, const float* __restrict__ m2,
    const float* __restrict__ v2,
    float* __restrict__ bias1, float* __restrict__ W2f, float* __restrict__ bias2)
{
  int t = threadIdx.x;
  {
    float s = g1[t] * rsqrtf(v1[t] + BN_EPS);
    bias1[t] = b1[t] - m1[t] * s;
  }
  for (int i = t; i < 2304; i += 256) {
    int j = i >> 8;
    float s2 = g2[j] * rsqrtf(v2[j] + BN_EPS);
    W2f[i] = W2[i] * s2;
  }
  if (t < 9) {
    float s2 = g2[t] * rsqrtf(v2[t] + BN_EPS);
    bias2[t] = b2[t] - m2[t] * s2;
  }
}

// ---------------------------------------------------------------------------
// K1: fold scale1 into W1, quantize bf16, transpose to Bt[o][tap*256 + i]
// One block per output channel o; coalesced read + coalesced write.
__global__ __launch_bounds__(256) void fold_w1_kernel(
    const float* __restrict__ W1, const float* __restrict__ g1,
    const float* __restrict__ v1, unsigned short* __restrict__ Bt)
{
  int o = blockIdx.x;           // 0..255
  int t = threadIdx.x;          // = input channel i
  float s = g1[o] * rsqrtf(v1[o] + BN_EPS);
  const float* src = W1 + (size_t)o * 2304 + (size_t)t * 9;
  float wv[9];
  #pragma unroll
  for (int tap = 0; tap < 9; ++tap) wv[tap] = src[tap] * s;
  unsigned short* dst = Bt + (size_t)o * 2304 + t;
  #pragma unroll
  for (int tap = 0; tap < 9; ++tap) dst[tap * 256] = f2bf(wv[tap]);
}

// ---------------------------------------------------------------------------
// K1b: zero only the pad border of yTp
__global__ __launch_bounds__(256) void border_zero_kernel(unsigned short* __restrict__ yTp)
{
  int n = blockIdx.x, t = threadIdx.x;
  size_t base = (size_t)n * 66 * 66 * 256;
  u16x8 z = (u16x8){0, 0, 0, 0, 0, 0, 0, 0};
  for (int i = t; i < 2112; i += 256) {
    *(u16x8*)(yTp + base + (size_t)i * 8) = z;
    *(u16x8*)(yTp + base + (size_t)65 * 66 * 256 + (size_t)i * 8) = z;
  }
  for (int i = t; i < 2048; i += 256) {
    int hh = 1 + (i >> 5);
    int off = (i & 31) * 8;
    *(u16x8*)(yTp + base + ((size_t)hh * 66 + 0) * 256 + off) = z;
    *(u16x8*)(yTp + base + ((size_t)hh * 66 + 65) * 256 + off) = z;
  }
}

// ---------------------------------------------------------------------------
// K2: y (fp32 NCHW) -> zero-padded bf16 NHWC yTp[n][hh][ww][c]
// Coalesced float4 reads + coalesced u16x8 writes (LDS transpose).
__global__ __launch_bounds__(256) void transpose_pad_kernel(
    const float* __restrict__ y, unsigned short* __restrict__ yTp)
{
  __shared__ unsigned short T[64][68];   // [c_local][w]
  int t = threadIdx.x;
  int nb = blockIdx.x; int n = nb >> 6, h = nb & 63;
  int w4 = (t & 15) * 4;
  int cl = t >> 4;
  for (int cb = 0; cb < 4; ++cb) {
    __syncthreads();
    #pragma unroll
    for (int r = 0; r < 4; ++r) {
      int c = cb * 64 + cl + r * 16;
      float4 v = *(const float4*)(y + ((((size_t)n * 256 + c) * 64 + h) << 6) + w4);
      u16x4 pv = { f2bf(v.x), f2bf(v.y), f2bf(v.z), f2bf(v.w) };
      *(u16x4*)&T[cl + r * 16][w4] = pv;
    }
    __syncthreads();
    size_t base = (((size_t)n * 66 + (h + 1)) * 66 + 1) * 256 + cb * 64;
    #pragma unroll
    for (int pass = 0; pass < 2; ++pass) {
      int w = pass * 32 + (t >> 3);
      int c8 = (t & 7) * 8;
      u16x8 o;
      #pragma unroll
      for (int i = 0; i < 8; ++i) o[i] = T[c8 + i][w];
      *(u16x8*)(yTp + base + (size_t)w * 256 + c8) = o;
    }
  }
}

// ---------------------------------------------------------------------------
// K3: conv3x3 implicit GEMM. Block = 128 pixels (2 h-rows) x 256 couts.
// Outer: 8 channel chunks (32ch) -> stage A (4 rows x 66 px) ONCE in LDS.
// Inner: 9 taps -> stream B via global_load_lds, 32 MFMA/wave, tap-shifted
// A fragments from LDS. A global traffic = 135 KB/block, read exactly once.
__global__ __launch_bounds__(256, 2) void conv3x3_mfma_kernel(
    const unsigned short* __restrict__ yTp, const unsigned short* __restrict__ Bt,
    const float* __restrict__ bias1, const float* __restrict__ a1p,
    unsigned short* __restrict__ hT)
{
  __shared__ unsigned short Als[4][4][66][8];  // [q][row][px][8ch] 16.5 KB
  __shared__ unsigned short Bls[4][256][8];    // [q][cout][8ch]    16 KB
  int tid = threadIdx.x;
  int w = tid >> 6, l = tid & 63;
  int lr = l & 15, quad = l >> 4;
  int wm = w >> 1, wn = w & 1;                 // 2x2 waves over (M=128, N=256)
  int bm = blockIdx.x;                         // 0..511
  int n = bm >> 5, hb = (bm & 31) * 2;

  f32x4 acc[4][8];
  #pragma unroll
  for (int im = 0; im < 4; ++im)
    #pragma unroll
    for (int in_ = 0; in_ < 8; ++in_)
      acc[im][in_] = (f32x4){0.f, 0.f, 0.f, 0.f};

  const size_t nb66 = (size_t)n * 66;

  for (int chunk = 0; chunk < 8; ++chunk) {
    int ci0 = chunk * 32;
    #pragma unroll 1
    for (int tap = 0; tap < 9; ++tap) {
      int ti = tap / 3;
      int tj = tap - 3 * ti;
      __syncthreads();
      if (tap == 0) {
        // A stage: wave w -> padded row hb+w, px = lane (0..63)
        const unsigned short* ga =
            yTp + (((nb66 + hb + w) * 66 + l) << 8) + ci0;
        #pragma unroll
        for (int q = 0; q < 4; ++q)
          async_ld16(ga + q * 8, &Als[q][w][0][0]);
        if (tid < 32) {   // px 64,65 tail
          int q = tid >> 3, rr = (tid >> 1) & 3, pxl = 64 + (tid & 1);
          u16x8 v = *(const u16x8*)(
              yTp + (((nb66 + hb + rr) * 66 + pxl) << 8) + ci0 + q * 8);
          *(u16x8*)&Als[q][rr][pxl][0] = v;
        }
      }
      // B stage: wave w -> couts w*64..w*64+64
      const unsigned short* gb =
          Bt + (size_t)(w * 64 + l) * 2304 + tap * 256 + ci0;
      #pragma unroll
      for (int q = 0; q < 4; ++q)
        async_ld16(gb + q * 8, &Bls[q][w * 64][0]);
      __syncthreads();
      // compute: 4 x 8 MFMA
      bf16x8 af[4], bfr[8];
      #pragma unroll
      for (int im = 0; im < 4; ++im)
        af[im] = *(const bf16x8*)&Als[quad][wm + ti][im * 16 + lr + tj][0];
      #pragma unroll
      for (int in_ = 0; in_ < 8; ++in_)
        bfr[in_] = *(const bf16x8*)&Bls[quad][wn * 128 + in_ * 16 + lr][0];
      #pragma unroll
      for (int im = 0; im < 4; ++im)
        #pragma unroll
        for (int in_ = 0; in_ < 8; ++in_)
          acc[im][in_] = __builtin_amdgcn_mfma_f32_16x16x32_bf16(
              af[im], bfr[in_], acc[im][in_], 0, 0, 0);
    }
  }

  float a1 = a1p[0];
  size_t pix0 = (size_t)bm * 128 + wm * 64;
  #pragma unroll
  for (int in_ = 0; in_ < 8; ++in_) {
    int c = wn * 128 + in_ * 16 + lr;
    float bs = bias1[c];
    #pragma unroll
    for (int im = 0; im < 4; ++im) {
      size_t m0 = pix0 + im * 16 + quad * 4;
      #pragma unroll
      for (int r = 0; r < 4; ++r) {
        float v = acc[im][in_][r] + bs;
        v = (v >= 0.f) ? v : a1 * v;
        hT[(m0 + r) * 256 + c] = f2bf(v);
      }
    }
  }
}

// ---------------------------------------------------------------------------
// K4: 1x1 conv C->9 + BN + PReLU. 4 lanes per pixel, shfl reduce.
__global__ __launch_bounds__(256) void conv1x1_kernel(
    const unsigned short* __restrict__ hT, const float* __restrict__ W2f,
    const float* __restrict__ bias2, const float* __restrict__ a2p,
    float* __restrict__ kernP)
{
  __shared__ float w2s[2304];
  int t = threadIdx.x;
  for (int i = t; i < 2304; i += 256) w2s[i] = W2f[i];
  __syncthreads();
  int seg = t & 3;
  int pr = t >> 2;
  int p = blockIdx.x * 64 + pr;
  const unsigned short* hp = hT + (size_t)p * 256;
  float acc[9];
  #pragma unroll
  for (int j = 0; j < 9; ++j) acc[j] = 0.f;
  for (int c0 = seg * 8; c0 < 256; c0 += 32) {
    u16x8 hv = *(const u16x8*)(hp + c0);
    float hf[8];
    #pragma unroll
    for (int i = 0; i < 8; ++i) hf[i] = bf2f(hv[i]);
    #pragma unroll
    for (int j = 0; j < 9; ++j)
      #pragma unroll
      for (int i = 0; i < 8; ++i)
        acc[j] = fmaf(hf[i], w2s[j * 256 + c0 + i], acc[j]);
  }
  #pragma unroll
  for (int j = 0; j < 9; ++j) {
    acc[j] += __shfl_xor(acc[j], 1);
    acc[j] += __shfl_xor(acc[j], 2);
  }
  if (seg == 0) {
    float a2 = a2p[0];
    #pragma unroll
    for (int j = 0; j < 9; ++j) {
      float v = acc[j] + bias2[j];
      v = (v >= 0.f) ? v : a2 * v;
      kernP[j * 65536 + p] = v;
    }
  }
}

// ---------------------------------------------------------------------------
// K5: scrambled unfold-reshape apply (reference's row-major reshape).
__global__ __launch_bounds__(256) void apply_dyn_kernel(
    const float* __restrict__ x, const float* __restrict__ kernP,
    float* __restrict__ out)
{
  __shared__ float xs[64 * 65];
  __shared__ float ks[9][16];
  int t = threadIdx.x;
  int b = blockIdx.x;             // ((n*64 + h')*4 + g)
  int g = b & 3;
  int nh = b >> 2;
  int n = nh >> 6, hp = nh & 63;
  int c = 4 * hp + g;

  const float* xplane = x + (((size_t)n * 256 + c) << 12);
  for (int i = t; i < 1024; i += 256) {
    float4 v = *(const float4*)(xplane + i * 4);
    int row = i >> 4;
    int col = (i * 4) & 63;
    float* d = &xs[row * 65 + col];
    d[0] = v.x; d[1] = v.y; d[2] = v.z; d[3] = v.w;
  }
  int pbase = n * 4096 + hp * 64 + g * 16;
  for (int i = t; i < 144; i += 256)
    ks[i / 16][i & 15] = kernP[(i / 16) * 65536 + pbase + (i & 15)];
  __syncthreads();

  int s = t & 15;
  int crow = t >> 4;
  float ksr[9];
  #pragma unroll
  for (int k2 = 0; k2 < 9; ++k2) ksr[k2] = ks[k2][s];

  int r0base = s * 2304 + crow * 9;
  #pragma unroll 4
  for (int jj = 0; jj < 16; ++jj) {
    int cp = crow + 16 * jj;
    int r0 = r0base + 144 * jj;
    float acc = 0.f;
    #pragma unroll
    for (int k2 = 0; k2 < 9; ++k2) {
      int r = r0 + k2;
      int k = r >> 12;
      int rem = r & 4095;
      int h = rem >> 6;
      int w = rem & 63;
      int ti = k / 3;
      int tj = k - 3 * ti;
      int hh = h + ti - 1;
      int ww = w + tj - 1;
      float xv = 0.f;
      if ((unsigned)hh < 64u && (unsigned)ww < 64u) xv = xs[hh * 65 + ww];
      acc = fmaf(xv, ksr[k2], acc);
    }
    out[(((size_t)n * 256 + cp) << 12) + (hp << 6) + g * 16 + s] = acc;
  }
}

// ---------------------------------------------------------------------------
extern "C" void kernel_launch(void* const* d_in, const int* in_sizes, int n_in,
                              void* d_out, int out_size, void* d_ws, size_t ws_size,
                              hipStream_t stream) {
  const float* x  = (const float*)d_in[0];
  const float* y  = (const float*)d_in[1];
  const float* W1 = (const float*)d_in[2];
  const float* g1 = (const float*)d_in[3];
  const float* b1 = (const float*)d_in[4];
  const float* m1 = (const float*)d_in[5];
  const float* v1 = (const float*)d_in[6];
  const float* a1 = (const float*)d_in[7];
  const float* W2 = (const float*)d_in[8];
  const float* g2 = (const float*)d_in[9];
  const float* b2 = (const float*)d_in[10];
  const float* m2 = (const float*)d_in[11];
  const float* v2 = (const float*)d_in[12];
  const float* a2 = (const float*)d_in[13];
  float* out = (float*)d_out;

  char* ws = (char*)d_ws;
  size_t off = 0;
  const size_t yTp_bytes = (size_t)16 * 66 * 66 * 256 * 2;
  unsigned short* yTp = (unsigned short*)(ws + off); off += yTp_bytes;
  unsigned short* Bt  = (unsigned short*)(ws + off); off += (size_t)589824 * 2;
  unsigned short* hT  = (unsigned short*)(ws + off); off += (size_t)16777216 * 2;
  float* kernP = (float*)(ws + off); off += (size_t)589824 * 4;
  float* bias1 = (float*)(ws + off); off += 1024;
  float* W2f   = (float*)(ws + off); off += 9216;
  float* bias2 = (float*)(ws + off); off += 64;

  params_kernel<<<1, 256, 0, stream>>>(g1, b1, m1, v1, W2, g2, b2, m2, v2,
                                       bias1, W2f, bias2);
  fold_w1_kernel<<<256, 256, 0, stream>>>(W1, g1, v1, Bt);
  border_zero_kernel<<<16, 256, 0, stream>>>(yTp);
  transpose_pad_kernel<<<1024, 256, 0, stream>>>(y, yTp);
  conv3x3_mfma_kernel<<<512, 256, 0, stream>>>(yTp, Bt, bias1, a1, hT);
  conv1x1_kernel<<<1024, 256, 0, stream>>>(hT, W2f, bias2, a2, kernP);
  apply_dyn_kernel<<<4096, 256, 0, stream>>>(x, kernP, out);
}